// Round 3
// baseline (517.011 us; speedup 1.0000x reference)
//
#include <hip/hip_runtime.h>
#include <math.h>

// Problem geometry (compile-time constants from the reference)
#define BB 8
#define DD 472
#define CC 472
#define FH 56
#define FW 100
#define NPIX (FH * FW)          // 5600
#define NPIX_TOT (BB * NPIX)    // 44800
#define NX 160
#define NY 160
#define OUT_FLOATS ((size_t)BB * NX * NY * CC)   // 96,665,600
#define OUT_F4 (OUT_FLOATS / 4)                  // 24,166,400 float4s
#define CELL_BLOCKS (NPIX_TOT / 64)              // 700
#define ZERO_BLOCKS 2048

// ---------------------------------------------------------------------------
// Kernel A (fused):
//  - blocks [0, CELL_BLOCKS): per-pixel depth argmax + projection -> cell id
//    (combine = R K^-1 computed per-block in f64 in shared; bit-identical to
//     the round-1 passing geometry)
//  - blocks [CELL_BLOCKS, CELL_BLOCKS+ZERO_BLOCKS): float4 grid-stride zero
//    of the 386.6 MB output (replaces hipMemsetAsync, which showed 4x write
//    amplification: 1.547 GB WRITE_SIZE for a 386.6 MB buffer)
// ---------------------------------------------------------------------------
__global__ __launch_bounds__(256) void k_main(const float* __restrict__ dlog,
                                              const float* __restrict__ intrins,
                                              const float* __restrict__ rot,
                                              float* __restrict__ out,
                                              int* __restrict__ cells) {
    if (blockIdx.x >= CELL_BLOCKS) {
        // ---- zero role ----
        size_t tid = (size_t)(blockIdx.x - CELL_BLOCKS) * 256 + threadIdx.x;
        float4* o4 = (float4*)out;
        const float4 z = make_float4(0.f, 0.f, 0.f, 0.f);
        const size_t stride = (size_t)ZERO_BLOCKS * 256;
        for (size_t i = tid; i < OUT_F4; i += stride) o4[i] = z;
        return;
    }

    // ---- cells role ----
    __shared__ double sM[BB][9];     // combine matrices, all 8 batches
    __shared__ float s_best[4][64];
    __shared__ int   s_idx[4][64];

    if (threadIdx.x < BB) {
        const int b = threadIdx.x;
        const float* K = intrins + b * 9;
        const float* R = rot + b * 9;
        double a00 = K[0], a01 = K[1], a02 = K[2];
        double a10 = K[3], a11 = K[4], a12 = K[5];
        double a20 = K[6], a21 = K[7], a22 = K[8];
        double det = a00 * (a11 * a22 - a12 * a21)
                   - a01 * (a10 * a22 - a12 * a20)
                   + a02 * (a10 * a21 - a11 * a20);
        double inv[9];
        inv[0] =  (a11 * a22 - a12 * a21) / det;
        inv[1] = -(a01 * a22 - a02 * a21) / det;
        inv[2] =  (a01 * a12 - a02 * a11) / det;
        inv[3] = -(a10 * a22 - a12 * a20) / det;
        inv[4] =  (a00 * a22 - a02 * a20) / det;
        inv[5] = -(a00 * a12 - a02 * a10) / det;
        inv[6] =  (a10 * a21 - a11 * a20) / det;
        inv[7] = -(a00 * a21 - a01 * a20) / det;
        inv[8] =  (a00 * a11 - a01 * a10) / det;
        for (int i = 0; i < 3; ++i)
            for (int j = 0; j < 3; ++j) {
                double s = 0.0;
                for (int k = 0; k < 3; ++k)
                    s += (double)R[i * 3 + k] * inv[k * 3 + j];
                sM[b][i * 3 + j] = s;
            }
    }

    const int lane = threadIdx.x & 63;
    const int q = threadIdx.x >> 6;          // depth-chunk 0..3 (118 bins each)
    const int pid = blockIdx.x * 64 + lane;  // 700 blocks * 64 = 44800 exact
    const int b = pid / NPIX;
    const int rem = pid - b * NPIX;

    const float* base = dlog + (size_t)b * DD * NPIX + rem;
    float best = -INFINITY;
    int bi = 0;
    const int d0 = q * 118;
    #pragma unroll 4
    for (int k = 0; k < 118; ++k) {
        int dd = d0 + k;
        float v = base[(size_t)dd * NPIX];
        if (v > best) { best = v; bi = dd; }   // strict > : first max wins
    }
    s_best[q][lane] = best;
    s_idx[q][lane] = bi;
    __syncthreads();
    if (q != 0) return;

    // merge chunks ascending (preserves first-occurrence tiebreak)
    for (int qq = 1; qq < 4; ++qq) {
        float v = s_best[qq][lane];
        if (v > best) { best = v; bi = s_idx[qq][lane]; }
    }

    // geometry in f64 (tracks the numpy f64 reference's floor decisions)
    const int h = rem / FW;
    const int w = rem - h * FW;
    double d = (double)bi * 0.125 + 1.0;
    double u = (double)w * (1600.0 / 99.0);   // linspace(0,1600,100)
    double v2 = (double)h * (896.0 / 55.0);   // linspace(0,896,56)
    double x0 = u * d, x1 = v2 * d, x2 = d;
    const double* M = sM[b];
    double px = M[0] * x0 + M[1] * x1 + M[2] * x2;
    double py = M[3] * x0 + M[4] * x1 + M[5] * x2;
    double pz = M[6] * x0 + M[7] * x1 + M[8] * x2;

    bool ok = (px > 1.0) && (px < 41.0) &&
              (py > -20.0) && (py < 20.0) &&
              (pz > -10.0) && (pz < 10.0);
    int vx = (int)floor((px - 1.0) / 0.25);
    int vy = (int)floor((py + 20.0) / 0.25);
    int vz = (int)floor((pz + 10.0) / 20.0);
    ok = ok && (vx >= 0) && (vx < NX) && (vy >= 0) && (vy < NY) &&
         (vz >= 0) && (vz < 1);
    cells[pid] = ok ? (b * (NX * NY) + vx * NY + vy) : -1;
}

// ---------------------------------------------------------------------------
// Kernel B: scatter features of valid pixels into BEV cells (atomicAdd)
// Block = 256 threads = 16 consecutive pixels x 16 channel-lanes.
// ---------------------------------------------------------------------------
__global__ __launch_bounds__(256) void k_scatter(const float* __restrict__ feats,
                                                 const int* __restrict__ cells,
                                                 float* __restrict__ out) {
    const int tile = blockIdx.x;            // 2800 tiles of 16 pixels
    const int wi = threadIdx.x & 15;        // pixel within tile
    const int ci0 = threadIdx.x >> 4;       // channel phase 0..15
    const int pid = tile * 16 + wi;         // tiles never straddle a batch
    const int cell = cells[pid];

    if (!__any(cell >= 0)) return;          // whole-wave early out
    if (cell < 0) return;

    const int b = pid / NPIX;
    const int rem = pid - b * NPIX;
    const float* fb = feats + (size_t)b * CC * NPIX + rem;
    float* ob = out + (size_t)cell * CC;
    for (int c = ci0; c < CC; c += 16) {
        atomicAdd(ob + c, fb[(size_t)c * NPIX]);
    }
}

// ---------------------------------------------------------------------------
extern "C" void kernel_launch(void* const* d_in, const int* in_sizes, int n_in,
                              void* d_out, int out_size, void* d_ws, size_t ws_size,
                              hipStream_t stream) {
    const float* dlog    = (const float*)d_in[0];
    const float* feats   = (const float*)d_in[1];
    const float* intrins = (const float*)d_in[2];
    const float* rot     = (const float*)d_in[3];
    float* out = (float*)d_out;
    int* cells = (int*)d_ws;   // 44800 ints

    k_main<<<CELL_BLOCKS + ZERO_BLOCKS, 256, 0, stream>>>(dlog, intrins, rot, out, cells);
    k_scatter<<<NPIX_TOT / 16, 256, 0, stream>>>(feats, cells, out);
}